// Round 8
// baseline (99.347 us; speedup 1.0000x reference)
//
#include <hip/hip_runtime.h>

#define B_ 16
#define T_ 4096
#define D_ 128
#define L_ 128
#define NC_ 32            // T_/L_
#define CH_ (B_*NC_)      // 512 chunks
#define LDP 136

typedef __attribute__((ext_vector_type(8))) short bf16x8;
typedef __attribute__((ext_vector_type(4))) float f32x4;

__device__ __forceinline__ float clampf(float x, float lo, float hi) {
    return fminf(fmaxf(x, lo), hi);
}
__device__ __forceinline__ float phi_f(float x) {   // elu(x)+1
    return x > 0.f ? x + 1.f : __expf(x);
}
__device__ __forceinline__ unsigned short bf16r(float f) {  // RNE f32->bf16
    unsigned u = __builtin_bit_cast(unsigned, f);
    u += 0x7FFFu + ((u >> 16) & 1u);
    return (unsigned short)(u >> 16);
}
__device__ __forceinline__ float fbf(unsigned short h) {
    unsigned u = ((unsigned)h) << 16; return __builtin_bit_cast(float, u);
}
__device__ __forceinline__ unsigned pack2bf(float a, float b) {
    return (unsigned)bf16r(a) | ((unsigned)bf16r(b) << 16);
}
__device__ __forceinline__ uint4 pack8(const float* f) {
    uint4 r;
    r.x = pack2bf(f[0], f[1]); r.y = pack2bf(f[2], f[3]);
    r.z = pack2bf(f[4], f[5]); r.w = pack2bf(f[6], f[7]);
    return r;
}
__device__ __forceinline__ f32x4 zero4() { f32x4 z; z[0]=0.f; z[1]=0.f; z[2]=0.f; z[3]=0.f; return z; }

// A-layout (MFMA 16x16x32 A-operand) octet index for a 128(row) x 128(k) bf16 matrix:
//   octet(row, k0): flat = (((row>>4)*4 + (k0>>5))*64 + ((k0>>3)&3)*16 + (row&15))*8
//   element j: [row][k0 + j]
__device__ __forceinline__ size_t aidx(int row, int k0) {
    return (size_t)((((row >> 4) * 4 + (k0 >> 5)) * 64 + ((k0 >> 3) & 3) * 16 + (row & 15)) * 8);
}

// ================= k0w: cumlog decays + wexp =================
__global__ void k0w(const float* __restrict__ beta,
                    const float* __restrict__ bb1, const float* __restrict__ bb2,
                    float* __restrict__ lg1, float* __restrict__ lg2,
                    float* __restrict__ wexp) {
    int ch = blockIdx.x;
    int b = ch / NC_, c = ch % NC_;
    int tbase = b * T_ + c * L_;
    int tid = threadIdx.x;           // 0..127
    int lane = tid & 63, w = tid >> 6;
    __shared__ float tot1s[2], tot2s[2];

    float b1b = clampf(1.f / (1.f + __expf(-bb1[0])), 0.01f, 0.995f);
    float b2b = clampf(1.f / (1.f + __expf(-bb2[0])), 0.01f, 0.995f);
    float be = clampf(beta[tbase + tid], 0.01f, 0.995f);
    float x1 = __logf(clampf(b1b * be, 0.01f, 0.995f));
    float x2 = __logf(clampf(b2b * be, 0.01f, 0.995f));
#pragma unroll
    for (int off = 1; off < 64; off <<= 1) {
        float y1 = __shfl_up(x1, off);
        float y2 = __shfl_up(x2, off);
        if (lane >= off) { x1 += y1; x2 += y2; }
    }
    if (lane == 63) { tot1s[w] = x1; tot2s[w] = x2; }
    __syncthreads();
    if (w == 1) { x1 += tot1s[0]; x2 += tot2s[0]; }
    float tot1 = tot1s[0] + tot1s[1];
    float tot2 = tot2s[0] + tot2s[1];
    lg1[tbase + tid] = x1;
    lg2[tbase + tid] = x2;
    wexp[(size_t)ch * 128 + tid]                  = __expf(tot1 - x1);
    wexp[(size_t)CH_ * 128 + (size_t)ch * 128 + tid] = __expf(tot2 - x2);
}

// ================= kS: layout transforms, zero LDS =================
// grid 2048 = (chunk, quarter). Row-pass K -> phiKT; gathers -> phiKtT, VtT.
__global__ __launch_bounds__(256) void kS(
        const float* __restrict__ kk, const float* __restrict__ vv,
        const float* __restrict__ mask,
        unsigned short* __restrict__ phiKT, unsigned short* __restrict__ phiKtT,
        unsigned short* __restrict__ VtT) {
    int g = blockIdx.x;
    int ch = g >> 2, q = g & 3;
    int b = ch / NC_, c = ch % NC_;
    int tbase = b * T_ + c * L_;
    int tid = threadIdx.x;
    size_t cb = (size_t)ch * 16384;

    // ---- row-pass K: octets (s, d0), s in [q*32, q*32+32) ----
#pragma unroll
    for (int p = 0; p < 2; ++p) {
        int i = p * 256 + tid;                 // 0..511
        int s = q * 32 + (i >> 4), d0 = (i & 15) * 8;
        const float* kp = &kk[(size_t)(tbase + s) * D_ + d0];
        float4 x0 = *(const float4*)kp, x1 = *(const float4*)(kp + 4);
        float m = mask[tbase + s];
        float pq[8] = {phi_f(x0.x)*m, phi_f(x0.y)*m, phi_f(x0.z)*m, phi_f(x0.w)*m,
                       phi_f(x1.x)*m, phi_f(x1.y)*m, phi_f(x1.z)*m, phi_f(x1.w)*m};
        *(uint4*)&phiKT[cb + aidx(s, d0)] = pack8(pq);
    }

    // ---- K-gather: octets (d, s0), d in [q*32, q*32+32), lanes consecutive in d ----
#pragma unroll
    for (int p = 0; p < 2; ++p) {
        int i = p * 256 + tid;
        int d = q * 32 + (i & 31), s0 = (i >> 5) * 8;
        const float* kp = &kk[(size_t)(tbase + s0) * D_ + d];
        const float* mp = &mask[tbase + s0];
        float f[8];
#pragma unroll
        for (int j = 0; j < 8; ++j)
            f[j] = phi_f(kp[(size_t)j * D_]) * mp[j];
        *(uint4*)&phiKtT[cb + aidx(d, s0)] = pack8(f);
    }

    // ---- V-gather: octets (e, s0) ----
#pragma unroll
    for (int p = 0; p < 2; ++p) {
        int i = p * 256 + tid;
        int e = q * 32 + (i & 31), s0 = (i >> 5) * 8;
        const float* vp = &vv[(size_t)(tbase + s0) * D_ + e];
        float f[8];
#pragma unroll
        for (int j = 0; j < 8; ++j)
            f[j] = vp[(size_t)j * D_];
        *(uint4*)&VtT[cb + aidx(e, s0)] = pack8(f);
    }
}

// ================= kC: chunk-state GEMM + zc, k3-style global frags =================
__global__ __launch_bounds__(256, 2) void kC(
        const unsigned short* __restrict__ phiKtT, const unsigned short* __restrict__ VtT,
        const float* __restrict__ wexp,
        unsigned short* __restrict__ Cws, float* __restrict__ zc) {
    int ch = blockIdx.x, st = blockIdx.y;
    int b = ch / NC_, c = ch % NC_;
    int tid = threadIdx.x, lane = tid & 63, w = tid >> 6;
    int l15 = lane & 15, lg4 = lane >> 4;
    size_t cb = (size_t)ch * 16384;
    __shared__ unsigned short sC[16384];

    const float* wp = &wexp[(size_t)st * CH_ * 128 + (size_t)ch * 128];
    float wv[4][8];
#pragma unroll
    for (int ks = 0; ks < 4; ++ks) {
        float4 a0 = *(const float4*)&wp[ks * 32 + lg4 * 8];
        float4 a1 = *(const float4*)&wp[ks * 32 + lg4 * 8 + 4];
        wv[ks][0] = a0.x; wv[ks][1] = a0.y; wv[ks][2] = a0.z; wv[ks][3] = a0.w;
        wv[ks][4] = a1.x; wv[ks][5] = a1.y; wv[ks][6] = a1.z; wv[ks][7] = a1.w;
    }

    f32x4 acc[2][8];
#pragma unroll
    for (int mm = 0; mm < 2; ++mm)
#pragma unroll
        for (int n = 0; n < 8; ++n) acc[mm][n] = zero4();
    float zp[8] = {0.f, 0.f, 0.f, 0.f, 0.f, 0.f, 0.f, 0.f};

#pragma unroll
    for (int ks = 0; ks < 4; ++ks) {
        // A: w-scaled V^T fragments (e-tiles 2w, 2w+1)
        bf16x8 as[2];
#pragma unroll
        for (int mm = 0; mm < 2; ++mm) {
            bf16x8 vt = *(const bf16x8*)&VtT[cb + (size_t)((((w * 2 + mm) * 4 + ks) * 64 + lane) * 8)];
#pragma unroll
            for (int j = 0; j < 8; ++j)
                as[mm][j] = (short)bf16r(fbf((unsigned short)vt[j]) * wv[ks][j]);
        }
        // B: raw phiKt fragments (all 8 d-tiles)
        bf16x8 bb[8];
#pragma unroll
        for (int n = 0; n < 8; ++n)
            bb[n] = *(const bf16x8*)&phiKtT[cb + (size_t)(((n * 4 + ks) * 64 + lane) * 8)];
        if (w == 0) {
#pragma unroll
            for (int n = 0; n < 8; ++n)
#pragma unroll
                for (int j = 0; j < 8; ++j)
                    zp[n] += wv[ks][j] * fbf((unsigned short)bb[n][j]);
        }
#pragma unroll
        for (int n = 0; n < 8; ++n) {
            acc[0][n] = __builtin_amdgcn_mfma_f32_16x16x32_bf16(as[0], bb[n], acc[0][n], 0, 0, 0);
            acc[1][n] = __builtin_amdgcn_mfma_f32_16x16x32_bf16(as[1], bb[n], acc[1][n], 0, 0, 0);
        }
    }

    // zc store (wave 0 has full B coverage; reduce over lg4)
    if (w == 0) {
#pragma unroll
        for (int n = 0; n < 8; ++n) {
            float z = zp[n];
            z += __shfl_xor(z, 16); z += __shfl_xor(z, 32);
            if (lg4 == 0)
                zc[((size_t)(st * B_ + b) * NC_ + c) * D_ + n * 16 + l15] = z;
        }
    }

    // Ct writeback: scalar LDS scatter (A-layout), coalesced global emit
#pragma unroll
    for (int mm = 0; mm < 2; ++mm)
#pragma unroll
        for (int n = 0; n < 8; ++n)
#pragma unroll
            for (int r = 0; r < 4; ++r) {
                int e = (w * 2 + mm) * 16 + lg4 * 4 + r;
                int d = n * 16 + l15;
                sC[aidx(e, d & ~7) + (d & 7)] = bf16r(acc[mm][n][r]);
            }
    __syncthreads();
    unsigned short* Cp = Cws + ((size_t)(st * B_ + b) * NC_ + c) * (D_ * D_);
#pragma unroll
    for (int p = 0; p < 8; ++p) {
        int i = tid + p * 256;
        *(uint4*)&Cp[(size_t)i * 8] = *(const uint4*)&sC[i * 8];
    }
}

// ================= k2f: chunk-state scans (unchanged) =================
__global__ void k2f(unsigned short* __restrict__ Cws, float* __restrict__ zc,
                    const float* __restrict__ lg1, const float* __restrict__ lg2) {
    int g = blockIdx.x * blockDim.x + threadIdx.x;
    if (g < 131072) {            // Cws part: 2*B*D*D/4
        int st = g >> 16;
        int rem = g & 65535;
        int b = rem >> 12;
        int de = (rem & 4095) * 4;
        const float* lg = st ? lg2 : lg1;
        size_t base = ((size_t)(st * B_ + b) * NC_) * (D_ * D_) + de;
        float run0 = 0.f, run1 = 0.f, run2 = 0.f, run3 = 0.f;
        for (int c = 0; c < NC_; c++) {
            float a = __expf(lg[b * T_ + c * L_ + L_ - 1]);
            uint2 val = *(uint2*)&Cws[base + (size_t)c * (D_ * D_)];
            float t0 = fbf((unsigned short)(val.x & 0xffff)), t1 = fbf((unsigned short)(val.x >> 16));
            float t2 = fbf((unsigned short)(val.y & 0xffff)), t3 = fbf((unsigned short)(val.y >> 16));
            uint2 wv; wv.x = pack2bf(run0, run1); wv.y = pack2bf(run2, run3);
            *(uint2*)&Cws[base + (size_t)c * (D_ * D_)] = wv;
            run0 = a * run0 + t0; run1 = a * run1 + t1;
            run2 = a * run2 + t2; run3 = a * run3 + t3;
        }
    } else {                     // zc part: 2*B*D threads
        int gz = g - 131072;
        int st = gz >> 11;
        int rem = gz & 2047;
        int b = rem >> 7;
        int d = rem & 127;
        const float* lg = st ? lg2 : lg1;
        size_t base = ((size_t)(st * B_ + b) * NC_) * D_ + d;
        float run = 0.f;
        for (int c = 0; c < NC_; c++) {
            float a = __expf(lg[b * T_ + c * L_ + L_ - 1]);
            float tmp = zc[base + (size_t)c * D_];
            zc[base + (size_t)c * D_] = run;
            run = a * run + tmp;
        }
    }
}

// ================= k3: one block per chunk, 2 t-tiles/wave, deep batching (unchanged) ===
__global__ __launch_bounds__(256, 2) void k3_v6(
        const float* __restrict__ qq, const float* __restrict__ mask,
        const float* __restrict__ lg1, const float* __restrict__ lg2,
        const unsigned short* __restrict__ phiKT, const unsigned short* __restrict__ VtT,
        const unsigned short* __restrict__ Cws, const float* __restrict__ zc,
        float* __restrict__ out) {
    __shared__ unsigned short bufP[4][32 * LDP];   // per-wave P^T (32 t-rows x 128 s)
    int ch = blockIdx.x;
    int b = ch / NC_, c = ch % NC_;
    int tbase = b * T_ + c * L_;
    int tid = threadIdx.x, lane = tid & 63, w = tid >> 6;
    int l15 = lane & 15, lg4 = lane >> 4;
    unsigned short* bufPw = &bufP[w][0];
    size_t cb = (size_t)ch * 16384;

    int trow0 = w * 16 + l15, trow1 = 64 + trow0;
    size_t gt0 = (size_t)(tbase + trow0), gt1 = (size_t)(tbase + trow1);

    float lg1t0 = lg1[gt0], lg2t0 = lg2[gt0], mt0 = mask[gt0];
    float lg1t1 = lg1[gt1], lg2t1 = lg2[gt1], mt1 = mask[gt1];
    float a1t0 = __expf(lg1t0), a2t0 = __expf(lg2t0);
    float a1t1 = __expf(lg1t1), a2t1 = __expf(lg2t1);

    // ---- phiQ B-fragments (both t-tiles) ----
    bf16x8 qf0[4], qf1[4];
#pragma unroll
    for (int ks = 0; ks < 4; ++ks) {
        int koff = ks * 32 + lg4 * 8;
        const float* qp0 = &qq[gt0 * D_ + koff];
        const float* qp1 = &qq[gt1 * D_ + koff];
        float4 x0 = *(const float4*)qp0, x1 = *(const float4*)(qp0 + 4);
        float4 y0 = *(const float4*)qp1, y1 = *(const float4*)(qp1 + 4);
        float p0[8] = {phi_f(x0.x), phi_f(x0.y), phi_f(x0.z), phi_f(x0.w),
                       phi_f(x1.x), phi_f(x1.y), phi_f(x1.z), phi_f(x1.w)};
        float p1[8] = {phi_f(y0.x), phi_f(y0.y), phi_f(y0.z), phi_f(y0.w),
                       phi_f(y1.x), phi_f(y1.y), phi_f(y1.z), phi_f(y1.w)};
#pragma unroll
        for (int j = 0; j < 8; ++j) {
            qf0[ks][j] = (short)bf16r(p0[j]);
            qf1[ks][j] = (short)bf16r(p1[j]);
        }
    }

    // ---- den inter-chunk dots ----
    const float* z1p = &zc[((size_t)(0 * B_ + b) * NC_ + c) * D_];
    const float* z2p = &zc[((size_t)(1 * B_ + b) * NC_ + c) * D_];
    float d1_0 = 0.f, d2_0 = 0.f, d1_1 = 0.f, d2_1 = 0.f;
#pragma unroll
    for (int ks = 0; ks < 4; ++ks) {
        int off = ks * 32 + lg4 * 8;
        float4 za = *(const float4*)(z1p + off), zb = *(const float4*)(z1p + off + 4);
        float4 zca = *(const float4*)(z2p + off), zcb = *(const float4*)(z2p + off + 4);
        float z1a[8] = {za.x, za.y, za.z, za.w, zb.x, zb.y, zb.z, zb.w};
        float z2a[8] = {zca.x, zca.y, zca.z, zca.w, zcb.x, zcb.y, zcb.z, zcb.w};
#pragma unroll
        for (int j = 0; j < 8; ++j) {
            float fq0 = fbf((unsigned short)qf0[ks][j]);
            float fq1 = fbf((unsigned short)qf1[ks][j]);
            d1_0 += fq0 * z1a[j]; d2_0 += fq0 * z2a[j];
            d1_1 += fq1 * z1a[j]; d2_1 += fq1 * z2a[j];
        }
    }
    d1_0 += __shfl_xor(d1_0, 16); d1_0 += __shfl_xor(d1_0, 32);
    d2_0 += __shfl_xor(d2_0, 16); d2_0 += __shfl_xor(d2_0, 32);
    d1_1 += __shfl_xor(d1_1, 16); d1_1 += __shfl_xor(d1_1, 32);
    d2_1 += __shfl_xor(d2_1, 16); d2_1 += __shfl_xor(d2_1, 32);

    // ---- S^T + P (per mh group of 4 s-tiles); kf batched 16-deep ----
    float rs0 = 0.f, rs1 = 0.f;
#pragma unroll
    for (int mh = 0; mh < 2; ++mh) {
        bf16x8 kf[16];
#pragma unroll
        for (int mm = 0; mm < 4; ++mm)
#pragma unroll
            for (int ks = 0; ks < 4; ++ks)
                kf[mm * 4 + ks] = *(const bf16x8*)&phiKT[cb + (size_t)(((((mh * 4 + mm) * 4) + ks) * 64 + lane) * 8)];
        f32x4 acc0[4], acc1[4];
#pragma unroll
        for (int mm = 0; mm < 4; ++mm) { acc0[mm] = zero4(); acc1[mm] = zero4(); }
#pragma unroll
        for (int ks = 0; ks < 4; ++ks)
#pragma unroll
            for (int mm = 0; mm < 4; ++mm) {
                if (mh == 0)
                    acc0[mm] = __builtin_amdgcn_mfma_f32_16x16x32_bf16(kf[mm * 4 + ks], qf0[ks], acc0[mm], 0, 0, 0);
                acc1[mm] = __builtin_amdgcn_mfma_f32_16x16x32_bf16(kf[mm * 4 + ks], qf1[ks], acc1[mm], 0, 0, 0);
            }
        // decay/mask -> P^T into bufP
#pragma unroll
        for (int mm = 0; mm < 4; ++mm) {
            int s0 = (mh * 4 + mm) * 16 + lg4 * 4;
            float4 l1s = *(const float4*)&lg1[tbase + s0];
            float4 l2s = *(const float4*)&lg2[tbase + s0];
            float l1a[4] = {l1s.x, l1s.y, l1s.z, l1s.w};
            float l2a[4] = {l2s.x, l2s.y, l2s.z, l2s.w};
            if (mh == 0) {
                float pv[4];
#pragma unroll
                for (int r = 0; r < 4; ++r) {
                    int s = s0 + r;
                    float p = 0.f;
                    if (s <= trow0)
                        p = acc0[mm][r] * (__expf(lg1t0 - l1a[r]) + __expf(lg2t0 - l2a[r]));
                    pv[r] = p; rs0 += p;
                }
                uint2 dd; dd.x = pack2bf(pv[0], pv[1]); dd.y = pack2bf(pv[2], pv[3]);
                *(uint2*)&bufPw[l15 * LDP + s0] = dd;
            }
            {
                float pv[4];
#pragma unroll
                for (int r = 0; r < 4; ++r) {
                    int s = s0 + r;
                    float p = 0.f;
                    if (s <= trow1)
                        p = acc1[mm][r] * (__expf(lg1t1 - l1a[r]) + __expf(lg2t1 - l2a[r]));
                    pv[r] = p; rs1 += p;
                }
                uint2 dd; dd.x = pack2bf(pv[0], pv[1]); dd.y = pack2bf(pv[2], pv[3]);
                *(uint2*)&bufPw[(16 + l15) * LDP + s0] = dd;
            }
        }
    }
    rs0 += __shfl_xor(rs0, 16); rs0 += __shfl_xor(rs0, 32);
    rs1 += __shfl_xor(rs1, 16); rs1 += __shfl_xor(rs1, 32);
    float osc0 = mt0 / fmaxf(a1t0 * d1_0 + a2t0 * d2_0 + rs0, 1e-6f);
    float osc1 = mt1 / fmaxf(a1t1 * d1_1 + a2t1 * d2_1 + rs1, 1e-6f);

    // ---- QH: acc += (a_st*phiQ) . H_st, hf batched 16-deep ----
    f32x4 acc_o0[8], acc_o1[8];
#pragma unroll
    for (int m = 0; m < 8; ++m) { acc_o0[m] = zero4(); acc_o1[m] = zero4(); }
#pragma unroll
    for (int st = 0; st < 2; ++st) {
        const unsigned short* Hp = Cws + ((size_t)(st * B_ + b) * NC_ + c) * (D_ * D_);
        float sc0 = st ? a2t0 : a1t0;
        float sc1 = st ? a2t1 : a1t1;
#pragma unroll
        for (int ks2 = 0; ks2 < 2; ++ks2) {
            bf16x8 hf[16];
#pragma unroll
            for (int kq = 0; kq < 2; ++kq)
#pragma unroll
                for (int m = 0; m < 8; ++m)
                    hf[kq * 8 + m] = *(const bf16x8*)&Hp[(size_t)(((m * 4 + ks2 * 2 + kq) * 64 + lane) * 8)];
#pragma unroll
            for (int kq = 0; kq < 2; ++kq) {
                int ks = ks2 * 2 + kq;
                bf16x8 qs0, qs1;
#pragma unroll
                for (int j = 0; j < 8; ++j) {
                    qs0[j] = (short)bf16r(fbf((unsigned short)qf0[ks][j]) * sc0);
                    qs1[j] = (short)bf16r(fbf((unsigned short)qf1[ks][j]) * sc1);
                }
#pragma unroll
                for (int m = 0; m < 8; ++m) {
                    acc_o0[m] = __builtin_amdgcn_mfma_f32_16x16x32_bf16(hf[kq * 8 + m], qs0, acc_o0[m], 0, 0, 0);
                    acc_o1[m] = __builtin_amdgcn_mfma_f32_16x16x32_bf16(hf[kq * 8 + m], qs1, acc_o1[m], 0, 0, 0);
                }
            }
        }
    }

    // ---- PV: acc += Vt @ P^T, vf batched 8-deep ----
#pragma unroll
    for (int ks = 0; ks < 4; ++ks) {
        bf16x8 vf[8];
#pragma unroll
        for (int m = 0; m < 8; ++m)
            vf[m] = *(const bf16x8*)&VtT[cb + (size_t)(((m * 4 + ks) * 64 + lane) * 8)];
        bf16x8 pf1 = *(const bf16x8*)&bufPw[(16 + l15) * LDP + ks * 32 + lg4 * 8];
        if (ks < 2) {
            bf16x8 pf0 = *(const bf16x8*)&bufPw[l15 * LDP + ks * 32 + lg4 * 8];
#pragma unroll
            for (int m = 0; m < 8; ++m)
                acc_o0[m] = __builtin_amdgcn_mfma_f32_16x16x32_bf16(vf[m], pf0, acc_o0[m], 0, 0, 0);
        }
#pragma unroll
        for (int m = 0; m < 8; ++m)
            acc_o1[m] = __builtin_amdgcn_mfma_f32_16x16x32_bf16(vf[m], pf1, acc_o1[m], 0, 0, 0);
    }

    // ---- store ----
#pragma unroll
    for (int m = 0; m < 8; ++m) {
        float4 o0, o1;
        o0.x = acc_o0[m][0] * osc0; o0.y = acc_o0[m][1] * osc0;
        o0.z = acc_o0[m][2] * osc0; o0.w = acc_o0[m][3] * osc0;
        o1.x = acc_o1[m][0] * osc1; o1.y = acc_o1[m][1] * osc1;
        o1.z = acc_o1[m][2] * osc1; o1.w = acc_o1[m][3] * osc1;
        *(float4*)&out[gt0 * D_ + m * 16 + lg4 * 4] = o0;
        *(float4*)&out[gt1 * D_ + m * 16 + lg4 * 4] = o1;
    }
}

extern "C" void kernel_launch(void* const* d_in, const int* in_sizes, int n_in,
                              void* d_out, int out_size, void* d_ws, size_t ws_size,
                              hipStream_t stream) {
    const float* q    = (const float*)d_in[0];
    const float* k    = (const float*)d_in[1];
    const float* v    = (const float*)d_in[2];
    const float* beta = (const float*)d_in[3];
    const float* mask = (const float*)d_in[4];
    const float* bb1  = (const float*)d_in[5];
    const float* bb2  = (const float*)d_in[6];
    float* out = (float*)d_out;

    size_t n_lg = (size_t)B_ * T_;                       // 65536
    size_t n_z  = (size_t)2 * B_ * NC_ * D_;             // 131072
    size_t n_w  = (size_t)2 * CH_ * 128;                 // 131072
    size_t n_C  = (size_t)2 * B_ * NC_ * D_ * D_;        // 16777216 bf16
    size_t n_kt = (size_t)B_ * T_ * D_;                  // 8388608 bf16
    size_t need = (2 * n_lg + n_z + n_w) * sizeof(float) + (n_C + 3 * n_kt) * sizeof(unsigned short);
    if (ws_size < need) return;

    float* lg1  = (float*)d_ws;
    float* lg2  = lg1 + n_lg;
    float* zc   = lg2 + n_lg;
    float* wexp = zc + n_z;
    unsigned short* Cws    = (unsigned short*)(wexp + n_w);
    unsigned short* phiKT  = Cws + n_C;
    unsigned short* phiKtT = phiKT + n_kt;
    unsigned short* VtT    = phiKtT + n_kt;

    k0w<<<CH_, 128, 0, stream>>>(beta, bb1, bb2, lg1, lg2, wexp);
    kS<<<4 * CH_, 256, 0, stream>>>(k, v, mask, phiKT, phiKtT, VtT);
    kC<<<dim3(CH_, 2), 256, 0, stream>>>(phiKtT, VtT, wexp, Cws, zc);
    k2f<<<528, 256, 0, stream>>>(Cws, zc, lg1, lg2);
    k3_v6<<<CH_, 256, 0, stream>>>(q, mask, lg1, lg2, phiKT, VtT, Cws, zc, out);
}

// Round 9
// 89.741 us; speedup vs baseline: 1.1070x; 1.1070x over previous
//
#include <hip/hip_runtime.h>

#define B_ 16
#define T_ 4096
#define D_ 128
#define L_ 128
#define NC_ 32            // T_/L_
#define CH_ (B_*NC_)      // 512 chunks
#define LDP 136

typedef __attribute__((ext_vector_type(8))) short bf16x8;
typedef __attribute__((ext_vector_type(4))) float f32x4;

__device__ __forceinline__ float clampf(float x, float lo, float hi) {
    return fminf(fmaxf(x, lo), hi);
}
__device__ __forceinline__ float phi_f(float x) {   // elu(x)+1
    return x > 0.f ? x + 1.f : __expf(x);
}
__device__ __forceinline__ unsigned short bf16r(float f) {  // RNE f32->bf16
    unsigned u = __builtin_bit_cast(unsigned, f);
    u += 0x7FFFu + ((u >> 16) & 1u);
    return (unsigned short)(u >> 16);
}
__device__ __forceinline__ float fbf(unsigned short h) {
    unsigned u = ((unsigned)h) << 16; return __builtin_bit_cast(float, u);
}
__device__ __forceinline__ unsigned pack2bf(float a, float b) {
    return (unsigned)bf16r(a) | ((unsigned)bf16r(b) << 16);
}
__device__ __forceinline__ uint4 pack8(const float* f) {
    uint4 r;
    r.x = pack2bf(f[0], f[1]); r.y = pack2bf(f[2], f[3]);
    r.z = pack2bf(f[4], f[5]); r.w = pack2bf(f[6], f[7]);
    return r;
}
__device__ __forceinline__ f32x4 zero4() { f32x4 z; z[0]=0.f; z[1]=0.f; z[2]=0.f; z[3]=0.f; return z; }

// A-layout (MFMA 16x16x32 A-operand) octet index for a 128(row) x 128(k) bf16 matrix:
//   octet(row, k0): flat = (((row>>4)*4 + (k0>>5))*64 + ((k0>>3)&3)*16 + (row&15))*8
//   element j: [row][k0 + j]
__device__ __forceinline__ int aidx(int row, int k0) {
    return (((row >> 4) * 4 + (k0 >> 5)) * 64 + ((k0 >> 3) & 3) * 16 + (row & 15)) * 8;
}

// ================= k0w: cumlog decays + wexp =================
__global__ void k0w(const float* __restrict__ beta,
                    const float* __restrict__ bb1, const float* __restrict__ bb2,
                    float* __restrict__ lg1, float* __restrict__ lg2,
                    float* __restrict__ wexp) {
    int ch = blockIdx.x;
    int b = ch / NC_, c = ch % NC_;
    int tbase = b * T_ + c * L_;
    int tid = threadIdx.x;           // 0..127
    int lane = tid & 63, w = tid >> 6;
    __shared__ float tot1s[2], tot2s[2];

    float b1b = clampf(1.f / (1.f + __expf(-bb1[0])), 0.01f, 0.995f);
    float b2b = clampf(1.f / (1.f + __expf(-bb2[0])), 0.01f, 0.995f);
    float be = clampf(beta[tbase + tid], 0.01f, 0.995f);
    float x1 = __logf(clampf(b1b * be, 0.01f, 0.995f));
    float x2 = __logf(clampf(b2b * be, 0.01f, 0.995f));
#pragma unroll
    for (int off = 1; off < 64; off <<= 1) {
        float y1 = __shfl_up(x1, off);
        float y2 = __shfl_up(x2, off);
        if (lane >= off) { x1 += y1; x2 += y2; }
    }
    if (lane == 63) { tot1s[w] = x1; tot2s[w] = x2; }
    __syncthreads();
    if (w == 1) { x1 += tot1s[0]; x2 += tot2s[0]; }
    float tot1 = tot1s[0] + tot1s[1];
    float tot2 = tot2s[0] + tot2s[1];
    lg1[tbase + tid] = x1;
    lg2[tbase + tid] = x2;
    wexp[(size_t)ch * 128 + tid]                     = __expf(tot1 - x1);
    wexp[(size_t)CH_ * 128 + (size_t)ch * 128 + tid] = __expf(tot2 - x2);
}

// ================= kS: phiKT row-pass + VtT gather, zero LDS =================
__global__ __launch_bounds__(256) void kS(
        const float* __restrict__ kk, const float* __restrict__ vv,
        const float* __restrict__ mask,
        unsigned short* __restrict__ phiKT, unsigned short* __restrict__ VtT) {
    int g = blockIdx.x;
    int ch = g >> 2, q = g & 3;
    int b = ch / NC_, c = ch % NC_;
    int tbase = b * T_ + c * L_;
    int tid = threadIdx.x;
    size_t cb = (size_t)ch * 16384;

    // ---- row-pass K: octets (s, d0), s in [q*32, q*32+32) ----
#pragma unroll
    for (int p = 0; p < 2; ++p) {
        int i = p * 256 + tid;                 // 0..511
        int s = q * 32 + (i >> 4), d0 = (i & 15) * 8;
        const float* kp = &kk[(size_t)(tbase + s) * D_ + d0];
        float4 x0 = *(const float4*)kp, x1 = *(const float4*)(kp + 4);
        float m = mask[tbase + s];
        float pq[8] = {phi_f(x0.x)*m, phi_f(x0.y)*m, phi_f(x0.z)*m, phi_f(x0.w)*m,
                       phi_f(x1.x)*m, phi_f(x1.y)*m, phi_f(x1.z)*m, phi_f(x1.w)*m};
        *(uint4*)&phiKT[cb + aidx(s, d0)] = pack8(pq);
    }

    // ---- V-gather: octets (e, s0), e in [q*32, q*32+32) ----
#pragma unroll
    for (int p = 0; p < 2; ++p) {
        int i = p * 256 + tid;
        int e = q * 32 + (i & 31), s0 = (i >> 5) * 8;
        const float* vp = &vv[(size_t)(tbase + s0) * D_ + e];
        float f[8];
#pragma unroll
        for (int j = 0; j < 8; ++j)
            f[j] = vp[(size_t)j * D_];
        *(uint4*)&VtT[cb + aidx(e, s0)] = pack8(f);
    }
}

// ================= kC: K-gather->LDS + chunk-state GEMM + zc =================
__global__ __launch_bounds__(256, 2) void kC(
        const float* __restrict__ kk, const float* __restrict__ mask,
        const unsigned short* __restrict__ VtT, const float* __restrict__ wexp,
        unsigned short* __restrict__ Cws, float* __restrict__ zc) {
    int ch = blockIdx.x;
    int b = ch / NC_, c = ch % NC_;
    int tbase = b * T_ + c * L_;
    int tid = threadIdx.x, lane = tid & 63, w = tid >> 6;
    int l15 = lane & 15, lg4 = lane >> 4;
    size_t cb = (size_t)ch * 16384;
    __shared__ unsigned short sKt[16384];   // 32 KB: phiK^T [d][s] in A-layout

    // ---- K-gather + phi + mask -> sKt (uint4 LDS writes, no scalar scatter) ----
#pragma unroll
    for (int p = 0; p < 8; ++p) {
        int i = p * 256 + tid;               // 2048 octets
        int d = i & 127, s0 = (i >> 7) * 8;
        const float* kp = &kk[(size_t)(tbase + s0) * D_ + d];
        const float* mp = &mask[tbase + s0];
        float f[8];
#pragma unroll
        for (int j = 0; j < 8; ++j)
            f[j] = phi_f(kp[(size_t)j * D_]) * mp[j];
        *(uint4*)&sKt[aidx(d, s0)] = pack8(f);
    }
    __syncthreads();

    const float* wp0 = &wexp[(size_t)ch * 128];
    const float* wp1 = &wexp[(size_t)CH_ * 128 + (size_t)ch * 128];

    f32x4 acc[2][2][8];
#pragma unroll
    for (int st = 0; st < 2; ++st)
#pragma unroll
        for (int mm = 0; mm < 2; ++mm)
#pragma unroll
            for (int n = 0; n < 8; ++n) acc[st][mm][n] = zero4();
    float zp[2][8];
#pragma unroll
    for (int st = 0; st < 2; ++st)
#pragma unroll
        for (int n = 0; n < 8; ++n) zp[st][n] = 0.f;

#pragma unroll
    for (int ks = 0; ks < 4; ++ks) {
        int koff = ks * 32 + lg4 * 8;
        float wl0[8], wl1[8];
        {
            float4 a0 = *(const float4*)&wp0[koff];
            float4 a1 = *(const float4*)&wp0[koff + 4];
            float4 b0 = *(const float4*)&wp1[koff];
            float4 b1 = *(const float4*)&wp1[koff + 4];
            wl0[0]=a0.x; wl0[1]=a0.y; wl0[2]=a0.z; wl0[3]=a0.w;
            wl0[4]=a1.x; wl0[5]=a1.y; wl0[6]=a1.z; wl0[7]=a1.w;
            wl1[0]=b0.x; wl1[1]=b0.y; wl1[2]=b0.z; wl1[3]=b0.w;
            wl1[4]=b1.x; wl1[5]=b1.y; wl1[6]=b1.z; wl1[7]=b1.w;
        }
        // A: w-scaled V^T fragments (e-tiles 2w, 2w+1) from global VtT
        bf16x8 as0[2], as1[2];
#pragma unroll
        for (int mm = 0; mm < 2; ++mm) {
            bf16x8 vt = *(const bf16x8*)&VtT[cb + (size_t)((((w * 2 + mm) * 4 + ks) * 64 + lane) * 8)];
#pragma unroll
            for (int j = 0; j < 8; ++j) {
                float av = fbf((unsigned short)vt[j]);
                as0[mm][j] = (short)bf16r(av * wl0[j]);
                as1[mm][j] = (short)bf16r(av * wl1[j]);
            }
        }
        // B: phiKt fragments from LDS (b128)
        bf16x8 bb[8];
#pragma unroll
        for (int n = 0; n < 8; ++n)
            bb[n] = *(const bf16x8*)&sKt[((n * 4 + ks) * 64 + lane) * 8];
        if (w == 0) {
#pragma unroll
            for (int n = 0; n < 8; ++n)
#pragma unroll
                for (int j = 0; j < 8; ++j) {
                    float kv = fbf((unsigned short)bb[n][j]);
                    zp[0][n] += wl0[j] * kv;
                    zp[1][n] += wl1[j] * kv;
                }
        }
#pragma unroll
        for (int n = 0; n < 8; ++n) {
            acc[0][0][n] = __builtin_amdgcn_mfma_f32_16x16x32_bf16(as0[0], bb[n], acc[0][0][n], 0, 0, 0);
            acc[0][1][n] = __builtin_amdgcn_mfma_f32_16x16x32_bf16(as0[1], bb[n], acc[0][1][n], 0, 0, 0);
            acc[1][0][n] = __builtin_amdgcn_mfma_f32_16x16x32_bf16(as1[0], bb[n], acc[1][0][n], 0, 0, 0);
            acc[1][1][n] = __builtin_amdgcn_mfma_f32_16x16x32_bf16(as1[1], bb[n], acc[1][1][n], 0, 0, 0);
        }
    }

    // zc store (wave 0; reduce over lg4)
    if (w == 0) {
#pragma unroll
        for (int st = 0; st < 2; ++st)
#pragma unroll
            for (int n = 0; n < 8; ++n) {
                float z = zp[st][n];
                z += __shfl_xor(z, 16); z += __shfl_xor(z, 32);
                if (lg4 == 0)
                    zc[((size_t)(st * B_ + b) * NC_ + c) * D_ + n * 16 + l15] = z;
            }
    }

    __syncthreads();   // all sKt GEMM reads done
    // ---- Ct writeback: LDS bounce per state, coalesced global emit ----
#pragma unroll
    for (int st = 0; st < 2; ++st) {
#pragma unroll
        for (int mm = 0; mm < 2; ++mm)
#pragma unroll
            for (int n = 0; n < 8; ++n)
#pragma unroll
                for (int r = 0; r < 4; ++r) {
                    int e = (w * 2 + mm) * 16 + lg4 * 4 + r;
                    int d = n * 16 + l15;
                    sKt[aidx(e, d & ~7) + (d & 7)] = bf16r(acc[st][mm][n][r]);
                }
        __syncthreads();
        unsigned short* Cp = Cws + ((size_t)(st * B_ + b) * NC_ + c) * (D_ * D_);
#pragma unroll
        for (int p = 0; p < 8; ++p) {
            int i = tid + p * 256;
            *(uint4*)&Cp[(size_t)i * 8] = *(const uint4*)&sKt[i * 8];
        }
        if (st == 0) __syncthreads();
    }
}

// ================= k2f: chunk-state scans (unchanged) =================
__global__ void k2f(unsigned short* __restrict__ Cws, float* __restrict__ zc,
                    const float* __restrict__ lg1, const float* __restrict__ lg2) {
    int g = blockIdx.x * blockDim.x + threadIdx.x;
    if (g < 131072) {            // Cws part: 2*B*D*D/4
        int st = g >> 16;
        int rem = g & 65535;
        int b = rem >> 12;
        int de = (rem & 4095) * 4;
        const float* lg = st ? lg2 : lg1;
        size_t base = ((size_t)(st * B_ + b) * NC_) * (D_ * D_) + de;
        float run0 = 0.f, run1 = 0.f, run2 = 0.f, run3 = 0.f;
        for (int c = 0; c < NC_; c++) {
            float a = __expf(lg[b * T_ + c * L_ + L_ - 1]);
            uint2 val = *(uint2*)&Cws[base + (size_t)c * (D_ * D_)];
            float t0 = fbf((unsigned short)(val.x & 0xffff)), t1 = fbf((unsigned short)(val.x >> 16));
            float t2 = fbf((unsigned short)(val.y & 0xffff)), t3 = fbf((unsigned short)(val.y >> 16));
            uint2 wv; wv.x = pack2bf(run0, run1); wv.y = pack2bf(run2, run3);
            *(uint2*)&Cws[base + (size_t)c * (D_ * D_)] = wv;
            run0 = a * run0 + t0; run1 = a * run1 + t1;
            run2 = a * run2 + t2; run3 = a * run3 + t3;
        }
    } else {                     // zc part: 2*B*D threads
        int gz = g - 131072;
        int st = gz >> 11;
        int rem = gz & 2047;
        int b = rem >> 7;
        int d = rem & 127;
        const float* lg = st ? lg2 : lg1;
        size_t base = ((size_t)(st * B_ + b) * NC_) * D_ + d;
        float run = 0.f;
        for (int c = 0; c < NC_; c++) {
            float a = __expf(lg[b * T_ + c * L_ + L_ - 1]);
            float tmp = zc[base + (size_t)c * D_];
            zc[base + (size_t)c * D_] = run;
            run = a * run + tmp;
        }
    }
}

// ================= k3: one block per chunk, 2 t-tiles/wave, deep batching (unchanged) ===
__global__ __launch_bounds__(256, 2) void k3_v6(
        const float* __restrict__ qq, const float* __restrict__ mask,
        const float* __restrict__ lg1, const float* __restrict__ lg2,
        const unsigned short* __restrict__ phiKT, const unsigned short* __restrict__ VtT,
        const unsigned short* __restrict__ Cws, const float* __restrict__ zc,
        float* __restrict__ out) {
    __shared__ unsigned short bufP[4][32 * LDP];   // per-wave P^T (32 t-rows x 128 s)
    int ch = blockIdx.x;
    int b = ch / NC_, c = ch % NC_;
    int tbase = b * T_ + c * L_;
    int tid = threadIdx.x, lane = tid & 63, w = tid >> 6;
    int l15 = lane & 15, lg4 = lane >> 4;
    unsigned short* bufPw = &bufP[w][0];
    size_t cb = (size_t)ch * 16384;

    int trow0 = w * 16 + l15, trow1 = 64 + trow0;
    size_t gt0 = (size_t)(tbase + trow0), gt1 = (size_t)(tbase + trow1);

    float lg1t0 = lg1[gt0], lg2t0 = lg2[gt0], mt0 = mask[gt0];
    float lg1t1 = lg1[gt1], lg2t1 = lg2[gt1], mt1 = mask[gt1];
    float a1t0 = __expf(lg1t0), a2t0 = __expf(lg2t0);
    float a1t1 = __expf(lg1t1), a2t1 = __expf(lg2t1);

    // ---- phiQ B-fragments (both t-tiles) ----
    bf16x8 qf0[4], qf1[4];
#pragma unroll
    for (int ks = 0; ks < 4; ++ks) {
        int koff = ks * 32 + lg4 * 8;
        const float* qp0 = &qq[gt0 * D_ + koff];
        const float* qp1 = &qq[gt1 * D_ + koff];
        float4 x0 = *(const float4*)qp0, x1 = *(const float4*)(qp0 + 4);
        float4 y0 = *(const float4*)qp1, y1 = *(const float4*)(qp1 + 4);
        float p0[8] = {phi_f(x0.x), phi_f(x0.y), phi_f(x0.z), phi_f(x0.w),
                       phi_f(x1.x), phi_f(x1.y), phi_f(x1.z), phi_f(x1.w)};
        float p1[8] = {phi_f(y0.x), phi_f(y0.y), phi_f(y0.z), phi_f(y0.w),
                       phi_f(y1.x), phi_f(y1.y), phi_f(y1.z), phi_f(y1.w)};
#pragma unroll
        for (int j = 0; j < 8; ++j) {
            qf0[ks][j] = (short)bf16r(p0[j]);
            qf1[ks][j] = (short)bf16r(p1[j]);
        }
    }

    // ---- den inter-chunk dots ----
    const float* z1p = &zc[((size_t)(0 * B_ + b) * NC_ + c) * D_];
    const float* z2p = &zc[((size_t)(1 * B_ + b) * NC_ + c) * D_];
    float d1_0 = 0.f, d2_0 = 0.f, d1_1 = 0.f, d2_1 = 0.f;
#pragma unroll
    for (int ks = 0; ks < 4; ++ks) {
        int off = ks * 32 + lg4 * 8;
        float4 za = *(const float4*)(z1p + off), zb = *(const float4*)(z1p + off + 4);
        float4 zca = *(const float4*)(z2p + off), zcb = *(const float4*)(z2p + off + 4);
        float z1a[8] = {za.x, za.y, za.z, za.w, zb.x, zb.y, zb.z, zb.w};
        float z2a[8] = {zca.x, zca.y, zca.z, zca.w, zcb.x, zcb.y, zcb.z, zcb.w};
#pragma unroll
        for (int j = 0; j < 8; ++j) {
            float fq0 = fbf((unsigned short)qf0[ks][j]);
            float fq1 = fbf((unsigned short)qf1[ks][j]);
            d1_0 += fq0 * z1a[j]; d2_0 += fq0 * z2a[j];
            d1_1 += fq1 * z1a[j]; d2_1 += fq1 * z2a[j];
        }
    }
    d1_0 += __shfl_xor(d1_0, 16); d1_0 += __shfl_xor(d1_0, 32);
    d2_0 += __shfl_xor(d2_0, 16); d2_0 += __shfl_xor(d2_0, 32);
    d1_1 += __shfl_xor(d1_1, 16); d1_1 += __shfl_xor(d1_1, 32);
    d2_1 += __shfl_xor(d2_1, 16); d2_1 += __shfl_xor(d2_1, 32);

    // ---- S^T + P (per mh group of 4 s-tiles); kf batched 16-deep ----
    float rs0 = 0.f, rs1 = 0.f;
#pragma unroll
    for (int mh = 0; mh < 2; ++mh) {
        bf16x8 kf[16];
#pragma unroll
        for (int mm = 0; mm < 4; ++mm)
#pragma unroll
            for (int ks = 0; ks < 4; ++ks)
                kf[mm * 4 + ks] = *(const bf16x8*)&phiKT[cb + (size_t)(((((mh * 4 + mm) * 4) + ks) * 64 + lane) * 8)];
        f32x4 acc0[4], acc1[4];
#pragma unroll
        for (int mm = 0; mm < 4; ++mm) { acc0[mm] = zero4(); acc1[mm] = zero4(); }
#pragma unroll
        for (int ks = 0; ks < 4; ++ks)
#pragma unroll
            for (int mm = 0; mm < 4; ++mm) {
                if (mh == 0)
                    acc0[mm] = __builtin_amdgcn_mfma_f32_16x16x32_bf16(kf[mm * 4 + ks], qf0[ks], acc0[mm], 0, 0, 0);
                acc1[mm] = __builtin_amdgcn_mfma_f32_16x16x32_bf16(kf[mm * 4 + ks], qf1[ks], acc1[mm], 0, 0, 0);
            }
        // decay/mask -> P^T into bufP
#pragma unroll
        for (int mm = 0; mm < 4; ++mm) {
            int s0 = (mh * 4 + mm) * 16 + lg4 * 4;
            float4 l1s = *(const float4*)&lg1[tbase + s0];
            float4 l2s = *(const float4*)&lg2[tbase + s0];
            float l1a[4] = {l1s.x, l1s.y, l1s.z, l1s.w};
            float l2a[4] = {l2s.x, l2s.y, l2s.z, l2s.w};
            if (mh == 0) {
                float pv[4];
#pragma unroll
                for (int r = 0; r < 4; ++r) {
                    int s = s0 + r;
                    float p = 0.f;
                    if (s <= trow0)
                        p = acc0[mm][r] * (__expf(lg1t0 - l1a[r]) + __expf(lg2t0 - l2a[r]));
                    pv[r] = p; rs0 += p;
                }
                uint2 dd; dd.x = pack2bf(pv[0], pv[1]); dd.y = pack2bf(pv[2], pv[3]);
                *(uint2*)&bufPw[l15 * LDP + s0] = dd;
            }
            {
                float pv[4];
#pragma unroll
                for (int r = 0; r < 4; ++r) {
                    int s = s0 + r;
                    float p = 0.f;
                    if (s <= trow1)
                        p = acc1[mm][r] * (__expf(lg1t1 - l1a[r]) + __expf(lg2t1 - l2a[r]));
                    pv[r] = p; rs1 += p;
                }
                uint2 dd; dd.x = pack2bf(pv[0], pv[1]); dd.y = pack2bf(pv[2], pv[3]);
                *(uint2*)&bufPw[(16 + l15) * LDP + s0] = dd;
            }
        }
    }
    rs0 += __shfl_xor(rs0, 16); rs0 += __shfl_xor(rs0, 32);
    rs1 += __shfl_xor(rs1, 16); rs1 += __shfl_xor(rs1, 32);
    float osc0 = mt0 / fmaxf(a1t0 * d1_0 + a2t0 * d2_0 + rs0, 1e-6f);
    float osc1 = mt1 / fmaxf(a1t1 * d1_1 + a2t1 * d2_1 + rs1, 1e-6f);

    // ---- QH: acc += (a_st*phiQ) . H_st, hf batched 16-deep ----
    f32x4 acc_o0[8], acc_o1[8];
#pragma unroll
    for (int m = 0; m < 8; ++m) { acc_o0[m] = zero4(); acc_o1[m] = zero4(); }
#pragma unroll
    for (int st = 0; st < 2; ++st) {
        const unsigned short* Hp = Cws + ((size_t)(st * B_ + b) * NC_ + c) * (D_ * D_);
        float sc0 = st ? a2t0 : a1t0;
        float sc1 = st ? a2t1 : a1t1;
#pragma unroll
        for (int ks2 = 0; ks2 < 2; ++ks2) {
            bf16x8 hf[16];
#pragma unroll
            for (int kq = 0; kq < 2; ++kq)
#pragma unroll
                for (int m = 0; m < 8; ++m)
                    hf[kq * 8 + m] = *(const bf16x8*)&Hp[(size_t)(((m * 4 + ks2 * 2 + kq) * 64 + lane) * 8)];
#pragma unroll
            for (int kq = 0; kq < 2; ++kq) {
                int ks = ks2 * 2 + kq;
                bf16x8 qs0, qs1;
#pragma unroll
                for (int j = 0; j < 8; ++j) {
                    qs0[j] = (short)bf16r(fbf((unsigned short)qf0[ks][j]) * sc0);
                    qs1[j] = (short)bf16r(fbf((unsigned short)qf1[ks][j]) * sc1);
                }
#pragma unroll
                for (int m = 0; m < 8; ++m) {
                    acc_o0[m] = __builtin_amdgcn_mfma_f32_16x16x32_bf16(hf[kq * 8 + m], qs0, acc_o0[m], 0, 0, 0);
                    acc_o1[m] = __builtin_amdgcn_mfma_f32_16x16x32_bf16(hf[kq * 8 + m], qs1, acc_o1[m], 0, 0, 0);
                }
            }
        }
    }

    // ---- PV: acc += Vt @ P^T, vf batched 8-deep ----
#pragma unroll
    for (int ks = 0; ks < 4; ++ks) {
        bf16x8 vf[8];
#pragma unroll
        for (int m = 0; m < 8; ++m)
            vf[m] = *(const bf16x8*)&VtT[cb + (size_t)(((m * 4 + ks) * 64 + lane) * 8)];
        bf16x8 pf1 = *(const bf16x8*)&bufPw[(16 + l15) * LDP + ks * 32 + lg4 * 8];
        if (ks < 2) {
            bf16x8 pf0 = *(const bf16x8*)&bufPw[l15 * LDP + ks * 32 + lg4 * 8];
#pragma unroll
            for (int m = 0; m < 8; ++m)
                acc_o0[m] = __builtin_amdgcn_mfma_f32_16x16x32_bf16(vf[m], pf0, acc_o0[m], 0, 0, 0);
        }
#pragma unroll
        for (int m = 0; m < 8; ++m)
            acc_o1[m] = __builtin_amdgcn_mfma_f32_16x16x32_bf16(vf[m], pf1, acc_o1[m], 0, 0, 0);
    }

    // ---- store ----
#pragma unroll
    for (int m = 0; m < 8; ++m) {
        float4 o0, o1;
        o0.x = acc_o0[m][0] * osc0; o0.y = acc_o0[m][1] * osc0;
        o0.z = acc_o0[m][2] * osc0; o0.w = acc_o0[m][3] * osc0;
        o1.x = acc_o1[m][0] * osc1; o1.y = acc_o1[m][1] * osc1;
        o1.z = acc_o1[m][2] * osc1; o1.w = acc_o1[m][3] * osc1;
        *(float4*)&out[gt0 * D_ + m * 16 + lg4 * 4] = o0;
        *(float4*)&out[gt1 * D_ + m * 16 + lg4 * 4] = o1;
    }
}

extern "C" void kernel_launch(void* const* d_in, const int* in_sizes, int n_in,
                              void* d_out, int out_size, void* d_ws, size_t ws_size,
                              hipStream_t stream) {
    const float* q    = (const float*)d_in[0];
    const float* k    = (const float*)d_in[1];
    const float* v    = (const float*)d_in[2];
    const float* beta = (const float*)d_in[3];
    const float* mask = (const float*)d_in[4];
    const float* bb1  = (const float*)d_in[5];
    const float* bb2  = (const float*)d_in[6];
    float* out = (float*)d_out;

    size_t n_lg = (size_t)B_ * T_;                       // 65536
    size_t n_z  = (size_t)2 * B_ * NC_ * D_;             // 131072
    size_t n_w  = (size_t)2 * CH_ * 128;                 // 131072
    size_t n_C  = (size_t)2 * B_ * NC_ * D_ * D_;        // 16777216 bf16
    size_t n_kt = (size_t)B_ * T_ * D_;                  // 8388608 bf16
    size_t need = (2 * n_lg + n_z + n_w) * sizeof(float) + (n_C + 2 * n_kt) * sizeof(unsigned short);
    if (ws_size < need) return;

    float* lg1  = (float*)d_ws;
    float* lg2  = lg1 + n_lg;
    float* zc   = lg2 + n_lg;
    float* wexp = zc + n_z;
    unsigned short* Cws    = (unsigned short*)(wexp + n_w);
    unsigned short* phiKT  = Cws + n_C;
    unsigned short* VtT    = phiKT + n_kt;

    k0w<<<CH_, 128, 0, stream>>>(beta, bb1, bb2, lg1, lg2, wexp);
    kS<<<4 * CH_, 256, 0, stream>>>(k, v, mask, phiKT, VtT);
    kC<<<CH_, 256, 0, stream>>>(k, mask, VtT, wexp, Cws, zc);
    k2f<<<528, 256, 0, stream>>>(Cws, zc, lg1, lg2);
    k3_v6<<<CH_, 256, 0, stream>>>(q, mask, lg1, lg2, phiKT, VtT, Cws, zc, out);
}